// Round 1
// baseline (167.726 us; speedup 1.0000x reference)
//
#include <hip/hip_runtime.h>

// Problem constants (logits: (16, 6, 512, 512) fp32, targets: (16, 512, 512) int)
#define BATCH 16
#define NCLS 6
#define HW 262144              // 512*512
#define BLOCKS_PER_B 64
#define THREADS 256
#define ITERS 4                // (HW/4) / (BLOCKS_PER_B*THREADS) = 65536/16384

#define NACC 19                // TP[6], p_sum[6], t_sum[6], ce

__global__ __launch_bounds__(THREADS) void loss_main(
    const float* __restrict__ logits,
    const int*   __restrict__ targets,
    float*       __restrict__ ws) {
    const int b   = blockIdx.y;
    const int tid = threadIdx.x;

    float acc[NACC];
    #pragma unroll
    for (int i = 0; i < NACC; ++i) acc[i] = 0.f;

    const float* lbase = logits + (size_t)b * NCLS * HW;
    const int4*  tbase = (const int4*)(targets + (size_t)b * HW);

    for (int k = 0; k < ITERS; ++k) {
        const int p4 = k * (BLOCKS_PER_B * THREADS) + blockIdx.x * THREADS + tid;

        float L[4][NCLS];
        #pragma unroll
        for (int c = 0; c < NCLS; ++c) {
            float4 v = ((const float4*)(lbase + (size_t)c * HW))[p4];
            L[0][c] = v.x; L[1][c] = v.y; L[2][c] = v.z; L[3][c] = v.w;
        }
        const int4 tv4 = tbase[p4];
        const int tgt[4] = {tv4.x, tv4.y, tv4.z, tv4.w};

        #pragma unroll
        for (int j = 0; j < 4; ++j) {
            float m = L[j][0];
            #pragma unroll
            for (int c = 1; c < NCLS; ++c) m = fmaxf(m, L[j][c]);

            float e[NCLS];
            float s = 0.f;
            #pragma unroll
            for (int c = 0; c < NCLS; ++c) { e[c] = __expf(L[j][c] - m); s += e[c]; }
            const float inv = 1.0f / s;
            const float lse = m + __logf(s);   // logZ

            #pragma unroll
            for (int c = 0; c < NCLS; ++c) {
                const float pr = e[c] * inv;
                acc[6 + c] += pr;                                  // p_sum
                const bool is_t = (tgt[j] == c);
                acc[c]      += is_t ? pr  : 0.f;                   // TP
                acc[12 + c] += is_t ? 1.f : 0.f;                   // t_sum
                acc[18]     += is_t ? (lse - L[j][c]) : 0.f;       // ce: -logp_t
            }
        }
    }

    // wave-64 butterfly reduce each accumulator
    #pragma unroll
    for (int i = 0; i < NACC; ++i) {
        float v = acc[i];
        v += __shfl_down(v, 32);
        v += __shfl_down(v, 16);
        v += __shfl_down(v, 8);
        v += __shfl_down(v, 4);
        v += __shfl_down(v, 2);
        v += __shfl_down(v, 1);
        acc[i] = v;
    }

    __shared__ float sacc[NACC];
    if (tid < NACC) sacc[tid] = 0.f;
    __syncthreads();
    if ((tid & 63) == 0) {
        #pragma unroll
        for (int i = 0; i < NACC; ++i) atomicAdd(&sacc[i], acc[i]);
    }
    __syncthreads();
    if (tid < NACC) atomicAdd(&ws[b * NACC + tid], sacc[tid]);
}

__global__ __launch_bounds__(128) void loss_finalize(
    const float* __restrict__ ws, float* __restrict__ out) {
    __shared__ float sd[128], sf[128], sc[128];
    const int i = threadIdx.x;
    float dice = 0.f, ft = 0.f, ce = 0.f;
    if (i < BATCH * NCLS) {
        const int b = i / NCLS, c = i % NCLS;
        const float* w = ws + b * NACC;
        const float TP = w[c], PS = w[6 + c], TS = w[12 + c];
        const float d = (2.f * TP + 1e-8f) / (PS + TS + 1e-8f);
        dice = 1.f - d;
        const float FP = PS - TP;
        const float FN = TS - TP;
        const float tv = (TP + 1e-6f) / (TP + 0.7f * FN + 0.3f * FP + 1e-6f);
        ft = powf(fmaxf(1.f - tv, 0.f), 1.33f);
    }
    if (i < BATCH) ce = ws[i * NACC + 18];
    sd[i] = dice; sf[i] = ft; sc[i] = ce;
    __syncthreads();
    for (int s = 64; s > 0; s >>= 1) {
        if (i < s) { sd[i] += sd[i + s]; sf[i] += sf[i + s]; sc[i] += sc[i + s]; }
        __syncthreads();
    }
    if (i == 0) {
        const float ce_mean   = sc[0] / (float)((size_t)BATCH * HW);
        const float dice_loss = sd[0] / (float)(BATCH * NCLS);
        const float ft_loss   = sf[0] / (float)(BATCH * NCLS);
        out[0] = 0.4f * ce_mean + 0.4f * dice_loss + 0.2f * ft_loss;
    }
}

extern "C" void kernel_launch(void* const* d_in, const int* in_sizes, int n_in,
                              void* d_out, int out_size, void* d_ws, size_t ws_size,
                              hipStream_t stream) {
    const float* logits  = (const float*)d_in[0];
    const int*   targets = (const int*)d_in[1];
    float*       ws      = (float*)d_ws;

    // harness poisons d_ws with 0xAA — zero the accumulator region (stream op, capture-safe)
    hipMemsetAsync(ws, 0, BATCH * NACC * sizeof(float), stream);

    loss_main<<<dim3(BLOCKS_PER_B, BATCH), THREADS, 0, stream>>>(logits, targets, ws);
    loss_finalize<<<1, 128, 0, stream>>>(ws, (float*)d_out);
}